// Round 13
// baseline (898.758 us; speedup 1.0000x reference)
//
#include <hip/hip_runtime.h>

typedef __attribute__((ext_vector_type(8))) short short8;
typedef __attribute__((ext_vector_type(4))) float f32x4;

#define B_EGO 8192
#define NSEQ  139264

// ---- workspace float offsets ----
#define WS_CONST 0         // 2432 floats: embT[448] eb[64] pe[256] bias[2][832]
#define WS_SIN   2432
#define WS_SOUT  14720
#define WS_G1    18816
#define WS_G2    27008
#define WS_T1    27392
#define WS_T1T   43776
#define WS_T2    44032
#define WS_PROB  47104
#define WS_H     47488
#define WS_NH    571776            // = WS_H + 8192*64
#define PACK_F   8960384           // ushort pack region (as float offset)
#define PACK_HL  49152             // ushorts per (layer, hi/lo plane)
#define PACK_PER_LAYER 98304       // ushorts per layer (hi + lo)

#define OUT_TRAJ  0
#define OUT_GOALS (B_EGO*72)
#define OUT_PROBS (OUT_GOALS + B_EGO*6)
#define OUT_ATTN  (OUT_PROBS + B_EGO*3)

#define MFMA(a,b,c) __builtin_amdgcn_mfma_f32_16x16x32_bf16(a,b,c,0,0,0)

__device__ __forceinline__ float dot4(float4 a, float4 b) {
  return a.x*b.x + a.y*b.y + a.z*b.z + a.w*b.w;
}
__device__ __forceinline__ unsigned short f2bf(float f) {   // RTNE, pure C
  unsigned int u = __float_as_uint(f);
  return (unsigned short)((u + 0x7FFFu + ((u >> 16) & 1u)) >> 16);
}
__device__ __forceinline__ float bfval(unsigned short h) {
  return __uint_as_float(((unsigned int)h) << 16);
}
// pack (a,b) -> {lo16=a, hi16=b} bf16 hi word (TRUNCATED) + RTNE residual word.
__device__ __forceinline__ void pksplit(float a, float b,
                                        unsigned int& hi, unsigned int& lo) {
  unsigned int ua = __float_as_uint(a), ub = __float_as_uint(b);
  hi = (ua >> 16) | (ub & 0xFFFF0000u);
  float ra = a - __uint_as_float(ua & 0xFFFF0000u);
  float rb = b - __uint_as_float(ub & 0xFFFF0000u);
  unsigned short al = f2bf(ra), bl = f2bf(rb);
  lo = (unsigned int)al | ((unsigned int)bl << 16);
}
__device__ __forceinline__ short8 mkfrag(unsigned int a, unsigned int b,
                                         unsigned int c, unsigned int d) {
  union { short8 s; unsigned int w[4]; } u;
  u.w[0] = a; u.w[1] = b; u.w[2] = c; u.w[3] = d;
  return u.s;
}

// ---------------------------------------------------------------------------
// prep: consts blob (embT, eb, pe rows 0-3, per-layer biases+ln)
// ---------------------------------------------------------------------------
__global__ void prep_consts(
    const float* __restrict__ embed_w, const float* __restrict__ embed_b,
    const float* __restrict__ pe,
    const float* __restrict__ attn_in_b, const float* __restrict__ attn_out_b,
    const float* __restrict__ ff1_b, const float* __restrict__ ff2_b,
    const float* __restrict__ ln1_g, const float* __restrict__ ln1_b,
    const float* __restrict__ ln2_g, const float* __restrict__ ln2_b,
    float* __restrict__ wsF)
{
  int idx = blockIdx.x * 256 + threadIdx.x;
  if (idx >= 2432) return;
  float v;
  if (idx < 448)      { int f = idx >> 6, c = idx & 63; v = embed_w[c*7 + f]; }
  else if (idx < 512) { v = embed_b[idx - 448]; }
  else if (idx < 768) { v = pe[idx - 512]; }
  else {
    int i = idx - 768, l = i / 832, j = i - l*832;
    if      (j < 192) v = attn_in_b [l*192 + j];
    else if (j < 256) v = attn_out_b[l*64  + j - 192];
    else if (j < 512) v = ff1_b     [l*256 + j - 256];
    else if (j < 576) v = ff2_b     [l*64  + j - 512];
    else if (j < 640) v = ln1_g     [l*64  + j - 576];
    else if (j < 704) v = ln1_b     [l*64  + j - 640];
    else if (j < 768) v = ln2_g     [l*64  + j - 704];
    else              v = ln2_b     [l*64  + j - 768];
  }
  wsF[idx] = v;
}

// ---------------------------------------------------------------------------
// prep: social-head fp32 packs
// ---------------------------------------------------------------------------
__global__ void prep_social(
    const float* __restrict__ soc_in_w, const float* __restrict__ soc_out_w,
    const float* __restrict__ goal1_w,  const float* __restrict__ goal2_w,
    const float* __restrict__ traj1_w,  const float* __restrict__ traj2_w,
    const float* __restrict__ prob_w,   float* __restrict__ wsF)
{
  int idx = blockIdx.x * 256 + threadIdx.x;
  if (idx >= 45056) return;
  float v; int t, i;
  if (idx < 12288) { t = idx; i = t & 3; t >>= 2; int o = t % 192, dc = t / 192;
    v = soc_in_w[o*64 + dc*4 + i]; }
  else if (idx < 16384) { t = idx - 12288; i = t & 3; t >>= 2; int o = t & 63, dc = t >> 6;
    v = soc_out_w[o*64 + dc*4 + i]; }
  else if (idx < 24576) { t = idx - 16384; i = t & 3; t >>= 2; int o = t & 63, dc = t >> 6;
    v = goal1_w[o*128 + dc*4 + i]; }
  else if (idx < 24960) { t = idx - 24576; i = t & 3; t >>= 2; int o = t % 6, dc = t / 6;
    v = goal2_w[o*64 + dc*4 + i]; }
  else if (idx < 41344) { t = idx - 24960; i = t & 3; t >>= 2; int o = t & 127, dc = t >> 7;
    v = traj1_w[o*130 + dc*4 + i]; }
  else if (idx < 41600) { t = idx - 41344; int o = t >> 1, j = t & 1;
    v = traj1_w[o*130 + 128 + j]; }
  else if (idx < 44672) { t = idx - 41600; i = t & 3; t >>= 2; int o = t % 24, dc = t / 24;
    v = traj2_w[o*128 + dc*4 + i]; }
  else { t = idx - 44672; i = t & 3; t >>= 2; int o = t % 3, dc = t / 3;
    v = prob_w[o*128 + dc*4 + i]; }
  wsF[WS_SIN + idx] = v;
}

// ---------------------------------------------------------------------------
// prep: bf16 MFMA fragment packs, DOUBLE-BF16 (hi plane + lo residual plane).
// sigma column permutation for X-LDS-k GEMMs: c = (e&3)*16 + ks*8 + 4*(e>>2) + g
// identity-k GEMMs (PO, P2):                  c = ks*32 + g*4 + (e&3) + 16*(e>>2)
// ---------------------------------------------------------------------------
__global__ void prep_mfma(
    const float* __restrict__ attn_in_w, const float* __restrict__ attn_out_w,
    const float* __restrict__ ff1_w,     const float* __restrict__ ff2_w,
    float* __restrict__ wsF)
{
  int idx = blockIdx.x * 256 + threadIdx.x;   // 98304 threads
  unsigned short* pw = (unsigned short*)(wsF + PACK_F);
  int l = idx / PACK_HL, r = idx - l*PACK_HL;
  int e = r & 7, lane = (r >> 3) & 63;
  int g = lane >> 4, l15 = lane & 15;
  float v;
  if (r < 12288) {                    // PQ / PK / PV (sigma)
    int which = r >> 12;              // 0=Q 1=K 2=V
    int ks = (r >> 9) & 1, t = (r >> 10) & 3;
    int c = (e & 3)*16 + ks*8 + 4*(e >> 2) + g;
    v = attn_in_w[l*12288 + (which*64 + t*16 + l15)*64 + c];
  } else if (r < 16384) {             // PO (identity)
    int r2 = r - 12288; int ks = (r2 >> 9) & 1, t = r2 >> 10;
    int c = ks*32 + g*4 + (e & 3) + 16*(e >> 2);
    v = attn_out_w[l*4096 + (t*16 + l15)*64 + c];
  } else if (r < 32768) {             // P1 (sigma)
    int r2 = r - 16384; int ks = (r2 >> 9) & 1, mt = r2 >> 10;
    int c = (e & 3)*16 + ks*8 + 4*(e >> 2) + g;
    v = ff1_w[l*16384 + (mt*16 + l15)*64 + c];
  } else {                            // P2 (identity, K=256)
    int r2 = r - 32768; int ks = (r2 >> 9) & 7, t = r2 >> 12;
    int c = ks*32 + g*4 + (e & 3) + 16*(e >> 2);
    v = ff2_w[l*16384 + (t*16 + l15)*256 + c];
  }
  unsigned short hw = f2bf(v);
  unsigned short lw = f2bf(v - bfval(hw));
  pw[l*PACK_PER_LAYER + r]           = hw;
  pw[l*PACK_PER_LAYER + PACK_HL + r] = lw;
}

// ---------------------------------------------------------------------------
// encode helpers (no macros, no asm)
// ---------------------------------------------------------------------------
__device__ __forceinline__ void lnorm(f32x4 xr[4], const float* cls,
                                      int gof, int bof, int l15) {
  float mean[4], rs[4];
  #pragma unroll
  for (int reg = 0; reg < 4; ++reg) {
    float s1 = xr[0][reg] + xr[1][reg] + xr[2][reg] + xr[3][reg];
    float s2 = xr[0][reg]*xr[0][reg] + xr[1][reg]*xr[1][reg]
             + xr[2][reg]*xr[2][reg] + xr[3][reg]*xr[3][reg];
    #pragma unroll
    for (int off = 1; off < 16; off <<= 1) {
      s1 += __shfl_xor(s1, off);
      s2 += __shfl_xor(s2, off);
    }
    float m = s1 * 0.015625f;
    float v = fmaxf(s2 * 0.015625f - m*m, 0.f);
    mean[reg] = m; rs[reg] = rsqrtf(v + 1e-5f);
  }
  #pragma unroll
  for (int t = 0; t < 4; ++t) {
    float gg = cls[gof + t*16 + l15], bb = cls[bof + t*16 + l15];
    #pragma unroll
    for (int reg = 0; reg < 4; ++reg)
      xr[t][reg] = (xr[t][reg] - mean[reg]) * rs[reg] * gg + bb;
  }
}

__device__ __forceinline__ void writeX(char* xbh, char* xbl,
                                       const f32x4 xr[4], int g, int l15) {
  #pragma unroll
  for (int reg = 0; reg < 4; ++reg) {
    int r = g*4 + reg;
    uint2 vh, vl;
    pksplit(xr[0][reg], xr[1][reg], vh.x, vl.x);
    pksplit(xr[2][reg], xr[3][reg], vh.y, vl.y);
    int off = (r*128 + l15*8) ^ ((r & 7) << 4);
    *(uint2*)(xbh + off) = vh;
    *(uint2*)(xbl + off) = vl;
  }
}

__device__ __forceinline__ void readX(const char* xbh, const char* xbl,
                                      short8 xah[2], short8 xal[2],
                                      int g, int l15) {
  #pragma unroll
  for (int ks = 0; ks < 2; ++ks) {
    int o1 = (l15*128 + ks*64 + g*8)      ^ ((l15 & 7) << 4);
    int o2 = (l15*128 + ks*64 + g*8 + 32) ^ ((l15 & 7) << 4);
    union { short8 s; uint2 d[2]; } uh, ul;
    uh.d[0] = *(const uint2*)(xbh + o1); uh.d[1] = *(const uint2*)(xbh + o2);
    ul.d[0] = *(const uint2*)(xbl + o1); ul.d[1] = *(const uint2*)(xbl + o2);
    xah[ks] = uh.s; xal[ks] = ul.s;
  }
}

// split a C-layout f32x4 pair into hi/lo A-fragments
__device__ __forceinline__ void splitA(const f32x4 a, const f32x4 b,
                                       short8& fh, short8& fl) {
  unsigned int w0, w1, w2, w3, z0, z1, z2, z3;
  pksplit(a[0], a[1], w0, z0);
  pksplit(a[2], a[3], w1, z1);
  pksplit(b[0], b[1], w2, z2);
  pksplit(b[2], b[3], w3, z3);
  fh = mkfrag(w0, w1, w2, w3);
  fl = mkfrag(z0, z1, z2, z3);
}

// ---------------------------------------------------------------------------
// encode: 1 wave = 8 seqs (2 tiles of 4 seqs x 4 tokens = 16 rows); every
// weight fragment loaded ONCE and applied to BOTH tiles. Per-sequence math
// is bit-identical to the R11-verified kernel (same fragments, same chain
// order); only scheduling/reuse changes. 3-MFMA double-bf16 products,
// residual/LN/softmax fp32. FF1->FF2 fused per hidden-pair (chain order
// preserved: h-chains identical, f2 accumulates ks8=0..7 in order).
// ---------------------------------------------------------------------------
__global__ __launch_bounds__(256) void encode_kernel(
    const float* __restrict__ xin, const float* __restrict__ nbr,
    const float* __restrict__ wsF, float* __restrict__ hout)
{
  __shared__ __align__(16) float cls[2432];
  __shared__ float tok_ls[4][224];
  __shared__ __align__(16) unsigned short xs[4][2][2048]; // [wave][tile][hi|lo]

  const int tid = threadIdx.x;
  const int w = tid >> 6, lane = tid & 63;
  const int g = lane >> 4, l15 = lane & 15;
  const f32x4 zero = {0.f, 0.f, 0.f, 0.f};

  for (int i = tid; i < 2432; i += 256) cls[i] = wsF[i];

  const int seq0w = blockIdx.x * 32 + w * 8;
  {
    const float* tokp = (blockIdx.x < 256) ? (xin + seq0w*28)
                                           : (nbr + (seq0w - B_EGO)*28);
    tok_ls[w][lane]       = tokp[lane];
    tok_ls[w][64 + lane]  = tokp[64 + lane];
    tok_ls[w][128 + lane] = tokp[128 + lane];
    if (lane < 32) tok_ls[w][192 + lane] = tokp[192 + lane];
  }
  __syncthreads();

  char* xb[2] = { (char*)xs[w][0], (char*)xs[w][1] };
  const unsigned short* pw = (const unsigned short*)(wsF + PACK_F);

  f32x4 xr[2][4];
  // ---- embed + pe (exact fp32, C-layout regs), per tile ----
  #pragma unroll
  for (int s = 0; s < 2; ++s) {
    float tk[4][7];
    #pragma unroll
    for (int reg = 0; reg < 4; ++reg)
      #pragma unroll
      for (int f = 0; f < 7; ++f)
        tk[reg][f] = tok_ls[w][s*112 + g*28 + reg*7 + f];
    #pragma unroll
    for (int t = 0; t < 4; ++t) {
      const int c = t*16 + l15;
      float we[7];
      #pragma unroll
      for (int f = 0; f < 7; ++f) we[f] = cls[f*64 + c];
      const float ebv = cls[448 + c];
      #pragma unroll
      for (int reg = 0; reg < 4; ++reg) {
        float acc = ebv + cls[512 + reg*64 + c];
        #pragma unroll
        for (int f = 0; f < 7; ++f) acc = fmaf(tk[reg][f], we[f], acc);
        xr[s][t][reg] = acc;
      }
    }
    writeX(xb[s], xb[s] + 2048, xr[s], g, l15);
  }

  #pragma unroll 1
  for (int ly = 0; ly < 2; ++ly) {
    const unsigned short* PLh = pw + ly*PACK_PER_LAYER;
    const unsigned short* PLl = PLh + PACK_HL;
    const int lb = 768 + ly*832;
    short8 xah[2][2], xal[2][2];
    #pragma unroll
    for (int s = 0; s < 2; ++s)
      readX(xb[s], xb[s] + 2048, xah[s], xal[s], g, l15);

    // ---- QKV: weights loaded once, applied to both tiles ----
    f32x4 q4[2][4], k4[2][4], v4[2][4];
    #pragma unroll
    for (int t = 0; t < 4; ++t) {
      #pragma unroll
      for (int s = 0; s < 2; ++s) { q4[s][t] = zero; k4[s][t] = zero; v4[s][t] = zero; }
      #pragma unroll
      for (int ks = 0; ks < 2; ++ks) {
        const int wo = ((t*2+ks)*64 + lane)*8;
        short8 aqh = *(const short8*)(PLh + wo);
        short8 aql = *(const short8*)(PLl + wo);
        short8 akh = *(const short8*)(PLh + 4096 + wo);
        short8 akl = *(const short8*)(PLl + 4096 + wo);
        short8 bvh = *(const short8*)(PLh + 8192 + wo);
        short8 bvl = *(const short8*)(PLl + 8192 + wo);
        #pragma unroll
        for (int s = 0; s < 2; ++s) {
          q4[s][t] = MFMA(aql, xah[s][ks], MFMA(aqh, xal[s][ks], MFMA(aqh, xah[s][ks], q4[s][t])));
          k4[s][t] = MFMA(akl, xah[s][ks], MFMA(akh, xal[s][ks], MFMA(akh, xah[s][ks], k4[s][t])));
          v4[s][t] = MFMA(xal[s][ks], bvh, MFMA(xah[s][ks], bvl, MFMA(xah[s][ks], bvh, v4[s][t])));
        }
      }
      f32x4 bq = *(const f32x4*)(&cls[lb +      t*16 + g*4]);
      f32x4 bk = *(const f32x4*)(&cls[lb + 64 + t*16 + g*4]);
      float bvv = cls[lb + 128 + t*16 + l15];
      #pragma unroll
      for (int s = 0; s < 2; ++s) {
        q4[s][t] += bq; k4[s][t] += bk;
        #pragma unroll
        for (int j = 0; j < 4; ++j) v4[s][t][j] += bvv;
      }
    }

    // ---- attention per tile (no weights) ----
    f32x4 oacc[2][4];
    const float vmask = (g == (l15 >> 2)) ? 1.f : 0.f;
    #pragma unroll
    for (int s = 0; s < 2; ++s) {
      #pragma unroll
      for (int h = 0; h < 4; ++h) {
        short8 aKh, aKl, bQh, bQl;
        splitA(k4[s][h], zero, aKh, aKl);
        splitA(q4[s][h], zero, bQh, bQl);
        f32x4 sa = MFMA(aKl, bQh, MFMA(aKh, bQl, MFMA(aKh, bQh, zero)));
        float s0 = sa[0]*0.25f, s1 = sa[1]*0.25f, s2 = sa[2]*0.25f, s3 = sa[3]*0.25f;
        float mx = fmaxf(fmaxf(s0, s1), fmaxf(s2, s3));
        float e0 = __expf(s0-mx), e1 = __expf(s1-mx), e2 = __expf(s2-mx), e3 = __expf(s3-mx);
        float inv = vmask / (e0 + e1 + e2 + e3);
        f32x4 pv = {e0*inv, e1*inv, e2*inv, e3*inv};
        short8 aVh, aVl, bPh, bPl;
        splitA(v4[s][h], zero, aVh, aVl);
        splitA(pv,       zero, bPh, bPl);
        oacc[s][h] = MFMA(aVl, bPh, MFMA(aVh, bPl, MFMA(aVh, bPh, zero)));
      }
    }

    // ---- out-proj: weights loaded once, applied to both tiles ----
    short8 aOh[2][2], aOl[2][2];
    #pragma unroll
    for (int s = 0; s < 2; ++s)
      #pragma unroll
      for (int ks = 0; ks < 2; ++ks)
        splitA(oacc[s][2*ks], oacc[s][2*ks+1], aOh[s][ks], aOl[s][ks]);
    #pragma unroll
    for (int t = 0; t < 4; ++t) {
      f32x4 fa[2] = {zero, zero};
      #pragma unroll
      for (int ks = 0; ks < 2; ++ks) {
        const int wo = 12288 + ((t*2+ks)*64 + lane)*8;
        short8 bOh = *(const short8*)(PLh + wo);
        short8 bOl = *(const short8*)(PLl + wo);
        #pragma unroll
        for (int s = 0; s < 2; ++s)
          fa[s] = MFMA(aOl[s][ks], bOh, MFMA(aOh[s][ks], bOl, MFMA(aOh[s][ks], bOh, fa[s])));
      }
      float bo = cls[lb + 192 + t*16 + l15];
      #pragma unroll
      for (int s = 0; s < 2; ++s)
        #pragma unroll
        for (int j = 0; j < 4; ++j) xr[s][t][j] += fa[s][j] + bo;
    }
    #pragma unroll
    for (int s = 0; s < 2; ++s) {
      lnorm(xr[s], cls, lb + 576, lb + 640, l15);
      writeX(xb[s], xb[s] + 2048, xr[s], g, l15);
      readX(xb[s], xb[s] + 2048, xah[s], xal[s], g, l15);
    }

    // ---- FF1+FF2 fused per hidden-pair; weights loaded once per pair ----
    f32x4 f2[2][4] = {{zero, zero, zero, zero}, {zero, zero, zero, zero}};
    #pragma unroll 1
    for (int ks8 = 0; ks8 < 8; ++ks8) {
      f32x4 ha[2] = {zero, zero}, hb[2] = {zero, zero};
      #pragma unroll
      for (int ks = 0; ks < 2; ++ks) {
        const int woa = 16384 + (((2*ks8  )*2+ks)*64 + lane)*8;
        const int wob = 16384 + (((2*ks8+1)*2+ks)*64 + lane)*8;
        short8 a1h = *(const short8*)(PLh + woa);
        short8 a1l = *(const short8*)(PLl + woa);
        short8 b1h = *(const short8*)(PLh + wob);
        short8 b1l = *(const short8*)(PLl + wob);
        #pragma unroll
        for (int s = 0; s < 2; ++s) {
          ha[s] = MFMA(a1l, xah[s][ks], MFMA(a1h, xal[s][ks], MFMA(a1h, xah[s][ks], ha[s])));
          hb[s] = MFMA(b1l, xah[s][ks], MFMA(b1h, xal[s][ks], MFMA(b1h, xah[s][ks], hb[s])));
        }
      }
      f32x4 ba = *(const f32x4*)(&cls[lb + 256 + (2*ks8  )*16 + g*4]);
      f32x4 bb = *(const f32x4*)(&cls[lb + 256 + (2*ks8+1)*16 + g*4]);
      short8 aHh[2], aHl[2];
      #pragma unroll
      for (int s = 0; s < 2; ++s) {
        #pragma unroll
        for (int j = 0; j < 4; ++j) {
          ha[s][j] = fmaxf(ha[s][j] + ba[j], 0.f);
          hb[s][j] = fmaxf(hb[s][j] + bb[j], 0.f);
        }
        splitA(ha[s], hb[s], aHh[s], aHl[s]);
      }
      #pragma unroll
      for (int t = 0; t < 4; ++t) {
        const int wo = 32768 + ((t*8+ks8)*64 + lane)*8;
        short8 b2h = *(const short8*)(PLh + wo);
        short8 b2l = *(const short8*)(PLl + wo);
        #pragma unroll
        for (int s = 0; s < 2; ++s)
          f2[s][t] = MFMA(aHl[s], b2h, MFMA(aHh[s], b2l, MFMA(aHh[s], b2h, f2[s][t])));
      }
    }
    #pragma unroll
    for (int s = 0; s < 2; ++s) {
      #pragma unroll
      for (int t = 0; t < 4; ++t) {
        float b2v = cls[lb + 512 + t*16 + l15];
        #pragma unroll
        for (int j = 0; j < 4; ++j) xr[s][t][j] += f2[s][t][j] + b2v;
      }
      lnorm(xr[s], cls, lb + 704, lb + 768, l15);
      writeX(xb[s], xb[s] + 2048, xr[s], g, l15);   // for next layer
    }
  }

  // ---- h = x[:, -1, :]  (token 3 = reg 3) ----
  #pragma unroll
  for (int s = 0; s < 2; ++s)
    #pragma unroll
    for (int t = 0; t < 4; ++t)
      hout[(seq0w + s*4 + g)*64 + t*16 + l15] = xr[s][t][3];
}

// ---------------------------------------------------------------------------
// social attention (Lq=1, Lk=16) + goal/traj/prob heads, one ego per wave.
// R11-verified: 4 waves, barriered, weight loops capped at unroll 4.
// ---------------------------------------------------------------------------
__global__ __launch_bounds__(256) void social_head_kernel(
    const float* __restrict__ ws,
    const float* __restrict__ soc_in_b, const float* __restrict__ soc_out_b,
    const float* __restrict__ goal1_b,  const float* __restrict__ goal2_b,
    const float* __restrict__ traj1_b,  const float* __restrict__ traj2_b,
    const float* __restrict__ prob_b,
    float* __restrict__ out)
{
  const float*  h    = ws + WS_H;
  const float*  nhp  = ws + WS_NH;
  const float4* sInP  = reinterpret_cast<const float4*>(ws + WS_SIN);
  const float4* sOutP = reinterpret_cast<const float4*>(ws + WS_SOUT);
  const float4* g1P   = reinterpret_cast<const float4*>(ws + WS_G1);
  const float4* g2P   = reinterpret_cast<const float4*>(ws + WS_G2);
  const float4* t1P   = reinterpret_cast<const float4*>(ws + WS_T1);
  const float*  t1T   = ws + WS_T1T;
  const float4* t2P   = reinterpret_cast<const float4*>(ws + WS_T2);
  const float4* pP    = reinterpret_cast<const float4*>(ws + WS_PROB);

  __shared__ __align__(16) float nls[4][16][64];
  __shared__ __align__(16) float kls[4][16][64];
  __shared__ __align__(16) float hfls[4][128];
  __shared__ __align__(16) float qls[4][64];
  __shared__ float als[4][64];
  __shared__ __align__(16) float ovls[4][64];
  __shared__ __align__(16) float g1ls[4][64];
  __shared__ __align__(16) float t1ls[4][128];
  __shared__ float gls[4][8];
  __shared__ float pls[4][4];

  const int w = threadIdx.x >> 6, lane = threadIdx.x & 63;
  const int b = blockIdx.x * 4 + w;

  hfls[w][lane] = h[b*64 + lane];
  #pragma unroll
  for (int t = 0; t < 16; ++t)
    nls[w][t][lane] = nhp[b*1024 + t*64 + lane];
  __syncthreads();

  float Q = soc_in_b[lane];
  #pragma unroll 4
  for (int dc = 0; dc < 16; ++dc)
    Q += dot4(*reinterpret_cast<const float4*>(&hfls[w][dc*4]), sInP[dc*192 + lane]);

  float Kv[16], Vv[16];
  {
    float bk = soc_in_b[64 + lane], bv = soc_in_b[128 + lane];
    #pragma unroll
    for (int k = 0; k < 16; ++k) { Kv[k] = bk; Vv[k] = bv; }
  }
  #pragma unroll 4
  for (int dc = 0; dc < 16; ++dc) {
    float4 wk = sInP[dc*192 + 64  + lane];
    float4 wv = sInP[dc*192 + 128 + lane];
    #pragma unroll
    for (int k = 0; k < 16; ++k) {
      float4 nv = *reinterpret_cast<const float4*>(&nls[w][k][dc*4]);
      Kv[k] += dot4(nv, wk);
      Vv[k] += dot4(nv, wv);
    }
  }
  qls[w][lane] = Q;
  #pragma unroll
  for (int k = 0; k < 16; ++k) kls[w][k][lane] = Kv[k];
  __syncthreads();

  {
    const int shh = lane >> 4, kk = lane & 15;
    float sc = 0.f;
    #pragma unroll
    for (int hd = 0; hd < 16; ++hd)
      sc += qls[w][shh*16 + hd] * kls[w][kk][shh*16 + hd];
    sc *= 0.25f;
    float m = sc;
    #pragma unroll
    for (int off = 1; off < 16; off <<= 1) m = fmaxf(m, __shfl_xor(m, off));
    float e = __expf(sc - m);
    float sm = e;
    #pragma unroll
    for (int off = 1; off < 16; off <<= 1) sm += __shfl_xor(sm, off);
    float a = e / sm;
    als[w][lane] = a;
    float am = a + __shfl_xor(a, 16);
    am += __shfl_xor(am, 32);
    if (lane < 16) out[OUT_ATTN + b*16 + lane] = 0.25f * am;
  }
  __syncthreads();

  {
    float ov = 0.f;
    #pragma unroll
    for (int k = 0; k < 16; ++k)
      ov += als[w][(lane & ~15) + k] * Vv[k];
    ovls[w][lane] = ov;
  }
  __syncthreads();
  {
    float soc = soc_out_b[lane];
    #pragma unroll 4
    for (int dc = 0; dc < 16; ++dc)
      soc += dot4(*reinterpret_cast<const float4*>(&ovls[w][dc*4]), sOutP[dc*64 + lane]);
    hfls[w][64 + lane] = soc;
  }
  __syncthreads();

  {
    float g1 = goal1_b[lane];
    #pragma unroll 4
    for (int dc = 0; dc < 32; ++dc)
      g1 += dot4(*reinterpret_cast<const float4*>(&hfls[w][dc*4]), g1P[dc*64 + lane]);
    g1ls[w][lane] = fmaxf(g1, 0.f);
  }
  __syncthreads();

  if (lane < 6) {
    float gv = goal2_b[lane];
    #pragma unroll 4
    for (int dc = 0; dc < 16; ++dc)
      gv += dot4(*reinterpret_cast<const float4*>(&g1ls[w][dc*4]), g2P[dc*6 + lane]);
    gls[w][lane] = gv;
    out[OUT_GOALS + b*6 + lane] = gv;
  } else if (lane >= 8 && lane < 11) {
    const int o = lane - 8;
    float pv = prob_b[o];
    #pragma unroll 4
    for (int dc = 0; dc < 32; ++dc)
      pv += dot4(*reinterpret_cast<const float4*>(&hfls[w][dc*4]), pP[dc*3 + o]);
    pls[w][o] = pv;
  }
  __syncthreads();
  if (lane < 3) {
    float p0 = pls[w][0], p1 = pls[w][1], p2 = pls[w][2];
    float mx = fmaxf(p0, fmaxf(p1, p2));
    float e0 = __expf(p0 - mx), e1 = __expf(p1 - mx), e2 = __expf(p2 - mx);
    float mine = (lane == 0) ? e0 : ((lane == 1) ? e1 : e2);
    out[OUT_PROBS + b*3 + lane] = mine / (e0 + e1 + e2);
  }

  for (int k3 = 0; k3 < 3; ++k3) {
    const float gx = gls[w][k3*2], gy = gls[w][k3*2 + 1];
    float t0 = traj1_b[lane], t1v = traj1_b[64 + lane];
    #pragma unroll 4
    for (int dc = 0; dc < 32; ++dc) {
      float4 xv = *reinterpret_cast<const float4*>(&hfls[w][dc*4]);
      t0  += dot4(xv, t1P[dc*128 + lane]);
      t1v += dot4(xv, t1P[dc*128 + 64 + lane]);
    }
    t0  += gx * t1T[lane*2]      + gy * t1T[lane*2 + 1];
    t1v += gx * t1T[(64+lane)*2] + gy * t1T[(64+lane)*2 + 1];
    t1ls[w][lane]      = fmaxf(t0, 0.f);
    t1ls[w][64 + lane] = fmaxf(t1v, 0.f);
    __syncthreads();
    if (lane < 24) {
      float tv = traj2_b[lane];
      #pragma unroll 4
      for (int dc = 0; dc < 32; ++dc)
        tv += dot4(*reinterpret_cast<const float4*>(&t1ls[w][dc*4]), t2P[dc*24 + lane]);
      out[OUT_TRAJ + b*72 + k3*24 + lane] = tv;
    }
    __syncthreads();
  }
}

// ---------------------------------------------------------------------------
extern "C" void kernel_launch(void* const* d_in, const int* in_sizes, int n_in,
                              void* d_out, int out_size, void* d_ws, size_t ws_size,
                              hipStream_t stream) {
  const float* xin        = (const float*)d_in[0];
  const float* neighbors  = (const float*)d_in[1];
  const float* pe         = (const float*)d_in[2];
  const float* embed_w    = (const float*)d_in[3];
  const float* embed_b    = (const float*)d_in[4];
  const float* attn_in_w  = (const float*)d_in[5];
  const float* attn_in_b  = (const float*)d_in[6];
  const float* attn_out_w = (const float*)d_in[7];
  const float* attn_out_b = (const float*)d_in[8];
  const float* ff1_w      = (const float*)d_in[9];
  const float* ff1_b      = (const float*)d_in[10];
  const float* ff2_w      = (const float*)d_in[11];
  const float* ff2_b      = (const float*)d_in[12];
  const float* ln1_g      = (const float*)d_in[13];
  const float* ln1_b      = (const float*)d_in[14];
  const float* ln2_g      = (const float*)d_in[15];
  const float* ln2_b      = (const float*)d_in[16];
  const float* soc_in_w   = (const float*)d_in[17];
  const float* soc_in_b   = (const float*)d_in[18];
  const float* soc_out_w  = (const float*)d_in[19];
  const float* soc_out_b  = (const float*)d_in[20];
  const float* goal1_w    = (const float*)d_in[21];
  const float* goal1_b    = (const float*)d_in[22];
  const float* goal2_w    = (const float*)d_in[23];
  const float* goal2_b    = (const float*)d_in[24];
  const float* traj1_w    = (const float*)d_in[25];
  const float* traj1_b    = (const float*)d_in[26];
  const float* traj2_w    = (const float*)d_in[27];
  const float* traj2_b    = (const float*)d_in[28];
  const float* prob_w     = (const float*)d_in[29];
  const float* prob_b     = (const float*)d_in[30];

  float* ws  = (float*)d_ws;
  float* out = (float*)d_out;

  prep_consts<<<10, 256, 0, stream>>>(embed_w, embed_b, pe, attn_in_b,
      attn_out_b, ff1_b, ff2_b, ln1_g, ln1_b, ln2_g, ln2_b, ws);
  prep_social<<<176, 256, 0, stream>>>(soc_in_w, soc_out_w, goal1_w, goal2_w,
      traj1_w, traj2_w, prob_w, ws);
  prep_mfma<<<384, 256, 0, stream>>>(attn_in_w, attn_out_w, ff1_w, ff2_w, ws);

  encode_kernel<<<NSEQ/32, 256, 0, stream>>>(xin, neighbors, ws, ws + WS_H);

  social_head_kernel<<<B_EGO/4, 256, 0, stream>>>(
      ws, soc_in_b, soc_out_b, goal1_b, goal2_b, traj1_b, traj2_b, prob_b, out);
}

// Round 16
// 841.518 us; speedup vs baseline: 1.0680x; 1.0680x over previous
//
#include <hip/hip_runtime.h>

typedef __attribute__((ext_vector_type(8))) short short8;
typedef __attribute__((ext_vector_type(4))) float f32x4;

#define B_EGO 8192
#define NSEQ  139264

// ---- workspace float offsets ----
#define WS_CONST 0         // 2432 floats: embT[448] eb[64] pe[256] bias[2][832]
#define WS_SIN   2432
#define WS_SOUT  14720
#define WS_G1    18816
#define WS_G2    27008
#define WS_T1    27392
#define WS_T1T   43776
#define WS_T2    44032
#define WS_PROB  47104
#define WS_H     47488
#define WS_NH    571776            // = WS_H + 8192*64
#define PACK_F   8960384           // ushort pack region (as float offset)
#define PACK_HL  49152             // ushorts per (layer, hi/lo plane)
#define PACK_PER_LAYER 98304       // ushorts per layer (hi + lo)

#define OUT_TRAJ  0
#define OUT_GOALS (B_EGO*72)
#define OUT_PROBS (OUT_GOALS + B_EGO*6)
#define OUT_ATTN  (OUT_PROBS + B_EGO*3)

#define MFMA(a,b,c) __builtin_amdgcn_mfma_f32_16x16x32_bf16(a,b,c,0,0,0)

__device__ __forceinline__ float dot4(float4 a, float4 b) {
  return a.x*b.x + a.y*b.y + a.z*b.z + a.w*b.w;
}
__device__ __forceinline__ unsigned short f2bf(float f) {   // RTNE, pure C
  unsigned int u = __float_as_uint(f);
  return (unsigned short)((u + 0x7FFFu + ((u >> 16) & 1u)) >> 16);
}
__device__ __forceinline__ float bfval(unsigned short h) {
  return __uint_as_float(((unsigned int)h) << 16);
}
// pack (a,b) -> {lo16=a, hi16=b} bf16 hi word (TRUNCATED) + RTNE residual word.
// (R7/R10/R11-verified variant)
__device__ __forceinline__ void pksplit(float a, float b,
                                        unsigned int& hi, unsigned int& lo) {
  unsigned int ua = __float_as_uint(a), ub = __float_as_uint(b);
  hi = (ua >> 16) | (ub & 0xFFFF0000u);
  float ra = a - __uint_as_float(ua & 0xFFFF0000u);
  float rb = b - __uint_as_float(ub & 0xFFFF0000u);
  unsigned short al = f2bf(ra), bl = f2bf(rb);
  lo = (unsigned int)al | ((unsigned int)bl << 16);
}
__device__ __forceinline__ short8 mkfrag(unsigned int a, unsigned int b,
                                         unsigned int c, unsigned int d) {
  union { short8 s; unsigned int w[4]; } u;
  u.w[0] = a; u.w[1] = b; u.w[2] = c; u.w[3] = d;
  return u.s;
}

// ---------------------------------------------------------------------------
// prep: consts blob (embT, eb, pe rows 0-3, per-layer biases+ln)
// ---------------------------------------------------------------------------
__global__ void prep_consts(
    const float* __restrict__ embed_w, const float* __restrict__ embed_b,
    const float* __restrict__ pe,
    const float* __restrict__ attn_in_b, const float* __restrict__ attn_out_b,
    const float* __restrict__ ff1_b, const float* __restrict__ ff2_b,
    const float* __restrict__ ln1_g, const float* __restrict__ ln1_b,
    const float* __restrict__ ln2_g, const float* __restrict__ ln2_b,
    float* __restrict__ wsF)
{
  int idx = blockIdx.x * 256 + threadIdx.x;
  if (idx >= 2432) return;
  float v;
  if (idx < 448)      { int f = idx >> 6, c = idx & 63; v = embed_w[c*7 + f]; }
  else if (idx < 512) { v = embed_b[idx - 448]; }
  else if (idx < 768) { v = pe[idx - 512]; }
  else {
    int i = idx - 768, l = i / 832, j = i - l*832;
    if      (j < 192) v = attn_in_b [l*192 + j];
    else if (j < 256) v = attn_out_b[l*64  + j - 192];
    else if (j < 512) v = ff1_b     [l*256 + j - 256];
    else if (j < 576) v = ff2_b     [l*64  + j - 512];
    else if (j < 640) v = ln1_g     [l*64  + j - 576];
    else if (j < 704) v = ln1_b     [l*64  + j - 640];
    else if (j < 768) v = ln2_g     [l*64  + j - 704];
    else              v = ln2_b     [l*64  + j - 768];
  }
  wsF[idx] = v;
}

// ---------------------------------------------------------------------------
// prep: social-head fp32 packs
// ---------------------------------------------------------------------------
__global__ void prep_social(
    const float* __restrict__ soc_in_w, const float* __restrict__ soc_out_w,
    const float* __restrict__ goal1_w,  const float* __restrict__ goal2_w,
    const float* __restrict__ traj1_w,  const float* __restrict__ traj2_w,
    const float* __restrict__ prob_w,   float* __restrict__ wsF)
{
  int idx = blockIdx.x * 256 + threadIdx.x;
  if (idx >= 45056) return;
  float v; int t, i;
  if (idx < 12288) { t = idx; i = t & 3; t >>= 2; int o = t % 192, dc = t / 192;
    v = soc_in_w[o*64 + dc*4 + i]; }
  else if (idx < 16384) { t = idx - 12288; i = t & 3; t >>= 2; int o = t & 63, dc = t >> 6;
    v = soc_out_w[o*64 + dc*4 + i]; }
  else if (idx < 24576) { t = idx - 16384; i = t & 3; t >>= 2; int o = t & 63, dc = t >> 6;
    v = goal1_w[o*128 + dc*4 + i]; }
  else if (idx < 24960) { t = idx - 24576; i = t & 3; t >>= 2; int o = t % 6, dc = t / 6;
    v = goal2_w[o*64 + dc*4 + i]; }
  else if (idx < 41344) { t = idx - 24960; i = t & 3; t >>= 2; int o = t & 127, dc = t >> 7;
    v = traj1_w[o*130 + dc*4 + i]; }
  else if (idx < 41600) { t = idx - 41344; int o = t >> 1, j = t & 1;
    v = traj1_w[o*130 + 128 + j]; }
  else if (idx < 44672) { t = idx - 41600; i = t & 3; t >>= 2; int o = t % 24, dc = t / 24;
    v = traj2_w[o*128 + dc*4 + i]; }
  else { t = idx - 44672; i = t & 3; t >>= 2; int o = t % 3, dc = t / 3;
    v = prob_w[o*128 + dc*4 + i]; }
  wsF[WS_SIN + idx] = v;
}

// ---------------------------------------------------------------------------
// prep: bf16 MFMA fragment packs, DOUBLE-BF16 (hi plane + lo residual plane).
// sigma column permutation for X-LDS-k GEMMs: c = (e&3)*16 + ks*8 + 4*(e>>2) + g
// identity-k GEMMs (PO, P2):                  c = ks*32 + g*4 + (e&3) + 16*(e>>2)
// ---------------------------------------------------------------------------
__global__ void prep_mfma(
    const float* __restrict__ attn_in_w, const float* __restrict__ attn_out_w,
    const float* __restrict__ ff1_w,     const float* __restrict__ ff2_w,
    float* __restrict__ wsF)
{
  int idx = blockIdx.x * 256 + threadIdx.x;   // 98304 threads
  unsigned short* pw = (unsigned short*)(wsF + PACK_F);
  int l = idx / PACK_HL, r = idx - l*PACK_HL;
  int e = r & 7, lane = (r >> 3) & 63;
  int g = lane >> 4, l15 = lane & 15;
  float v;
  if (r < 12288) {                    // PQ / PK / PV (sigma)
    int which = r >> 12;              // 0=Q 1=K 2=V
    int ks = (r >> 9) & 1, t = (r >> 10) & 3;
    int c = (e & 3)*16 + ks*8 + 4*(e >> 2) + g;
    v = attn_in_w[l*12288 + (which*64 + t*16 + l15)*64 + c];
  } else if (r < 16384) {             // PO (identity)
    int r2 = r - 12288; int ks = (r2 >> 9) & 1, t = r2 >> 10;
    int c = ks*32 + g*4 + (e & 3) + 16*(e >> 2);
    v = attn_out_w[l*4096 + (t*16 + l15)*64 + c];
  } else if (r < 32768) {             // P1 (sigma)
    int r2 = r - 16384; int ks = (r2 >> 9) & 1, mt = r2 >> 10;
    int c = (e & 3)*16 + ks*8 + 4*(e >> 2) + g;
    v = ff1_w[l*16384 + (mt*16 + l15)*64 + c];
  } else {                            // P2 (identity, K=256)
    int r2 = r - 32768; int ks = (r2 >> 9) & 7, t = r2 >> 12;
    int c = ks*32 + g*4 + (e & 3) + 16*(e >> 2);
    v = ff2_w[l*16384 + (t*16 + l15)*256 + c];
  }
  unsigned short hw = f2bf(v);
  unsigned short lw = f2bf(v - bfval(hw));
  pw[l*PACK_PER_LAYER + r]           = hw;
  pw[l*PACK_PER_LAYER + PACK_HL + r] = lw;
}

// ---------------------------------------------------------------------------
// encode helpers (no macros, no asm)
// ---------------------------------------------------------------------------
__device__ __forceinline__ void lnorm(f32x4 xr[4], const float* cls,
                                      int gof, int bof, int l15) {
  float mean[4], rs[4];
  #pragma unroll
  for (int reg = 0; reg < 4; ++reg) {
    float s1 = xr[0][reg] + xr[1][reg] + xr[2][reg] + xr[3][reg];
    float s2 = xr[0][reg]*xr[0][reg] + xr[1][reg]*xr[1][reg]
             + xr[2][reg]*xr[2][reg] + xr[3][reg]*xr[3][reg];
    #pragma unroll
    for (int off = 1; off < 16; off <<= 1) {
      s1 += __shfl_xor(s1, off);
      s2 += __shfl_xor(s2, off);
    }
    float m = s1 * 0.015625f;
    float v = fmaxf(s2 * 0.015625f - m*m, 0.f);
    mean[reg] = m; rs[reg] = rsqrtf(v + 1e-5f);
  }
  #pragma unroll
  for (int t = 0; t < 4; ++t) {
    float gg = cls[gof + t*16 + l15], bb = cls[bof + t*16 + l15];
    #pragma unroll
    for (int reg = 0; reg < 4; ++reg)
      xr[t][reg] = (xr[t][reg] - mean[reg]) * rs[reg] * gg + bb;
  }
}

__device__ __forceinline__ void writeX(char* xbh, char* xbl,
                                       const f32x4 xr[4], int g, int l15) {
  #pragma unroll
  for (int reg = 0; reg < 4; ++reg) {
    int r = g*4 + reg;
    uint2 vh, vl;
    pksplit(xr[0][reg], xr[1][reg], vh.x, vl.x);
    pksplit(xr[2][reg], xr[3][reg], vh.y, vl.y);
    int off = (r*128 + l15*8) ^ ((r & 7) << 4);
    *(uint2*)(xbh + off) = vh;
    *(uint2*)(xbl + off) = vl;
  }
}

__device__ __forceinline__ void readX(const char* xbh, const char* xbl,
                                      short8 xah[2], short8 xal[2],
                                      int g, int l15) {
  #pragma unroll
  for (int ks = 0; ks < 2; ++ks) {
    int o1 = (l15*128 + ks*64 + g*8)      ^ ((l15 & 7) << 4);
    int o2 = (l15*128 + ks*64 + g*8 + 32) ^ ((l15 & 7) << 4);
    union { short8 s; uint2 d[2]; } uh, ul;
    uh.d[0] = *(const uint2*)(xbh + o1); uh.d[1] = *(const uint2*)(xbh + o2);
    ul.d[0] = *(const uint2*)(xbl + o1); ul.d[1] = *(const uint2*)(xbl + o2);
    xah[ks] = uh.s; xal[ks] = ul.s;
  }
}

// split a C-layout f32x4 pair into hi/lo A-fragments
__device__ __forceinline__ void splitA(const f32x4 a, const f32x4 b,
                                       short8& fh, short8& fl) {
  unsigned int w0, w1, w2, w3, z0, z1, z2, z3;
  pksplit(a[0], a[1], w0, z0);
  pksplit(a[2], a[3], w1, z1);
  pksplit(b[0], b[1], w2, z2);
  pksplit(b[2], b[3], w3, z3);
  fh = mkfrag(w0, w1, w2, w3);
  fl = mkfrag(z0, z1, z2, z3);
}

// ---------------------------------------------------------------------------
// encode: 1 wave = 4 seqs x 4 tokens = 16 rows; all GEMMs via 3-MFMA
// double-bf16 products (Ah*Bh + Ah*Bl + Al*Bh), residual/LN/softmax fp32.
// (R11-verified verbatim; VGPR 124 / ~23% occupancy is the measured optimum.)
// ---------------------------------------------------------------------------
__global__ __launch_bounds__(256) void encode_kernel(
    const float* __restrict__ xin, const float* __restrict__ nbr,
    const float* __restrict__ wsF, float* __restrict__ hout)
{
  __shared__ __align__(16) float cls[2432];
  __shared__ float tok_ls[4][112];
  __shared__ __align__(16) unsigned short xs[4][2048];  // [hi 1024 | lo 1024]

  const int tid = threadIdx.x;
  const int w = tid >> 6, lane = tid & 63;
  const int g = lane >> 4, l15 = lane & 15;
  const f32x4 zero = {0.f, 0.f, 0.f, 0.f};

  for (int i = tid; i < 2432; i += 256) cls[i] = wsF[i];

  const int seq0w = blockIdx.x * 16 + w * 4;
  {
    const float* tokp = (blockIdx.x < 512) ? (xin + seq0w*28)
                                           : (nbr + (seq0w - B_EGO)*28);
    tok_ls[w][lane] = tokp[lane];
    if (lane < 48) tok_ls[w][64 + lane] = tokp[64 + lane];
  }
  __syncthreads();

  char* xbh = (char*)(xs[w]);
  char* xbl = xbh + 2048;
  const unsigned short* pw = (const unsigned short*)(wsF + PACK_F);

  f32x4 xr[4];
  // ---- embed + pe (exact fp32, C-layout regs) ----
  {
    float tk[4][7];
    #pragma unroll
    for (int reg = 0; reg < 4; ++reg)
      #pragma unroll
      for (int f = 0; f < 7; ++f)
        tk[reg][f] = tok_ls[w][g*28 + reg*7 + f];
    #pragma unroll
    for (int t = 0; t < 4; ++t) {
      const int c = t*16 + l15;
      float we[7];
      #pragma unroll
      for (int f = 0; f < 7; ++f) we[f] = cls[f*64 + c];
      const float ebv = cls[448 + c];
      #pragma unroll
      for (int reg = 0; reg < 4; ++reg) {
        float acc = ebv + cls[512 + reg*64 + c];
        #pragma unroll
        for (int f = 0; f < 7; ++f) acc = fmaf(tk[reg][f], we[f], acc);
        xr[t][reg] = acc;
      }
    }
  }
  writeX(xbh, xbl, xr, g, l15);

  #pragma unroll 1
  for (int ly = 0; ly < 2; ++ly) {
    const unsigned short* PLh = pw + ly*PACK_PER_LAYER;
    const unsigned short* PLl = PLh + PACK_HL;
    const int lb = 768 + ly*832;
    short8 xah[2], xal[2];
    readX(xbh, xbl, xah, xal, g, l15);

    // ---- QKV: Q^T = Wq·X^T, K^T = Wk·X^T (swapped), V = X·Wv^T ----
    f32x4 q4[4], k4[4], v4[4];
    #pragma unroll
    for (int t = 0; t < 4; ++t) {
      q4[t] = zero; k4[t] = zero; v4[t] = zero;
      #pragma unroll
      for (int ks = 0; ks < 2; ++ks) {
        const int wo = ((t*2+ks)*64 + lane)*8;
        short8 aqh = *(const short8*)(PLh + wo);
        short8 aql = *(const short8*)(PLl + wo);
        short8 akh = *(const short8*)(PLh + 4096 + wo);
        short8 akl = *(const short8*)(PLl + 4096 + wo);
        short8 bvh = *(const short8*)(PLh + 8192 + wo);
        short8 bvl = *(const short8*)(PLl + 8192 + wo);
        q4[t] = MFMA(aql, xah[ks], MFMA(aqh, xal[ks], MFMA(aqh, xah[ks], q4[t])));
        k4[t] = MFMA(akl, xah[ks], MFMA(akh, xal[ks], MFMA(akh, xah[ks], k4[t])));
        v4[t] = MFMA(xal[ks], bvh, MFMA(xah[ks], bvl, MFMA(xah[ks], bvh, v4[t])));
      }
      f32x4 bq = *(const f32x4*)(&cls[lb +      t*16 + g*4]);
      f32x4 bk = *(const f32x4*)(&cls[lb + 64 + t*16 + g*4]);
      q4[t] += bq; k4[t] += bk;
      float bvv = cls[lb + 128 + t*16 + l15];
      #pragma unroll
      for (int j = 0; j < 4; ++j) v4[t][j] += bvv;
    }

    // ---- attention: S^T = K·Q^T per head, in-lane softmax, O^T = V^T·P^T ----
    f32x4 oacc[4];
    const float vmask = (g == (l15 >> 2)) ? 1.f : 0.f;
    #pragma unroll
    for (int h = 0; h < 4; ++h) {
      short8 aKh, aKl, bQh, bQl;
      splitA(k4[h], zero, aKh, aKl);
      splitA(q4[h], zero, bQh, bQl);
      f32x4 sa = MFMA(aKl, bQh, MFMA(aKh, bQl, MFMA(aKh, bQh, zero)));
      float s0 = sa[0]*0.25f, s1 = sa[1]*0.25f, s2 = sa[2]*0.25f, s3 = sa[3]*0.25f;
      float mx = fmaxf(fmaxf(s0, s1), fmaxf(s2, s3));
      float e0 = __expf(s0-mx), e1 = __expf(s1-mx), e2 = __expf(s2-mx), e3 = __expf(s3-mx);
      float inv = vmask / (e0 + e1 + e2 + e3);
      f32x4 pv = {e0*inv, e1*inv, e2*inv, e3*inv};
      short8 aVh, aVl, bPh, bPl;
      splitA(v4[h], zero, aVh, aVl);
      splitA(pv,    zero, bPh, bPl);
      oacc[h] = MFMA(aVl, bPh, MFMA(aVh, bPl, MFMA(aVh, bPh, zero)));
    }

    // ---- out-proj: F = O·Wo^T (O^T C-regs are directly the A-fragment) ----
    short8 aOh[2], aOl[2];
    #pragma unroll
    for (int ks = 0; ks < 2; ++ks)
      splitA(oacc[2*ks], oacc[2*ks+1], aOh[ks], aOl[ks]);
    #pragma unroll
    for (int t = 0; t < 4; ++t) {
      f32x4 fa = zero;
      #pragma unroll
      for (int ks = 0; ks < 2; ++ks) {
        const int wo = 12288 + ((t*2+ks)*64 + lane)*8;
        short8 bOh = *(const short8*)(PLh + wo);
        short8 bOl = *(const short8*)(PLl + wo);
        fa = MFMA(aOl[ks], bOh, MFMA(aOh[ks], bOl, MFMA(aOh[ks], bOh, fa)));
      }
      float bo = cls[lb + 192 + t*16 + l15];
      #pragma unroll
      for (int j = 0; j < 4; ++j) xr[t][j] += fa[j] + bo;
    }
    lnorm(xr, cls, lb + 576, lb + 640, l15);

    writeX(xbh, xbl, xr, g, l15);
    readX(xbh, xbl, xah, xal, g, l15);

    // ---- FF1: H^T = relu(W1·X^T + b1) ----
    f32x4 h16[16];
    #pragma unroll
    for (int mt = 0; mt < 16; ++mt) {
      h16[mt] = zero;
      #pragma unroll
      for (int ks = 0; ks < 2; ++ks) {
        const int wo = 16384 + ((mt*2+ks)*64 + lane)*8;
        short8 a1h = *(const short8*)(PLh + wo);
        short8 a1l = *(const short8*)(PLl + wo);
        h16[mt] = MFMA(a1l, xah[ks], MFMA(a1h, xal[ks], MFMA(a1h, xah[ks], h16[mt])));
      }
      f32x4 b1 = *(const f32x4*)(&cls[lb + 256 + mt*16 + g*4]);
      #pragma unroll
      for (int j = 0; j < 4; ++j) h16[mt][j] = fmaxf(h16[mt][j] + b1[j], 0.f);
    }

    // ---- FF2: F = H·W2^T ----
    f32x4 f2[4] = {zero, zero, zero, zero};
    #pragma unroll
    for (int ks = 0; ks < 8; ++ks) {
      short8 aHh, aHl;
      splitA(h16[2*ks], h16[2*ks+1], aHh, aHl);
      #pragma unroll
      for (int t = 0; t < 4; ++t) {
        const int wo = 32768 + ((t*8+ks)*64 + lane)*8;
        short8 b2h = *(const short8*)(PLh + wo);
        short8 b2l = *(const short8*)(PLl + wo);
        f2[t] = MFMA(aHl, b2h, MFMA(aHh, b2l, MFMA(aHh, b2h, f2[t])));
      }
    }
    #pragma unroll
    for (int t = 0; t < 4; ++t) {
      float b2v = cls[lb + 512 + t*16 + l15];
      #pragma unroll
      for (int j = 0; j < 4; ++j) xr[t][j] += f2[t][j] + b2v;
    }
    lnorm(xr, cls, lb + 704, lb + 768, l15);

    writeX(xbh, xbl, xr, g, l15);   // for next layer (harmless on last)
  }

  // ---- h = x[:, -1, :]  (token 3 = reg 3) ----
  #pragma unroll
  for (int t = 0; t < 4; ++t)
    hout[(seq0w + g)*64 + t*16 + l15] = xr[t][3];
}

// ---------------------------------------------------------------------------
// social attention (Lq=1, Lk=16) + goal/traj/prob heads, one ego per wave.
// R11-verified: 4 waves, barriered, weight loops capped at unroll 4.
// ---------------------------------------------------------------------------
__global__ __launch_bounds__(256) void social_head_kernel(
    const float* __restrict__ ws,
    const float* __restrict__ soc_in_b, const float* __restrict__ soc_out_b,
    const float* __restrict__ goal1_b,  const float* __restrict__ goal2_b,
    const float* __restrict__ traj1_b,  const float* __restrict__ traj2_b,
    const float* __restrict__ prob_b,
    float* __restrict__ out)
{
  const float*  h    = ws + WS_H;
  const float*  nhp  = ws + WS_NH;
  const float4* sInP  = reinterpret_cast<const float4*>(ws + WS_SIN);
  const float4* sOutP = reinterpret_cast<const float4*>(ws + WS_SOUT);
  const float4* g1P   = reinterpret_cast<const float4*>(ws + WS_G1);
  const float4* g2P   = reinterpret_cast<const float4*>(ws + WS_G2);
  const float4* t1P   = reinterpret_cast<const float4*>(ws + WS_T1);
  const float*  t1T   = ws + WS_T1T;
  const float4* t2P   = reinterpret_cast<const float4*>(ws + WS_T2);
  const float4* pP    = reinterpret_cast<const float4*>(ws + WS_PROB);

  __shared__ __align__(16) float nls[4][16][64];
  __shared__ __align__(16) float kls[4][16][64];
  __shared__ __align__(16) float hfls[4][128];
  __shared__ __align__(16) float qls[4][64];
  __shared__ float als[4][64];
  __shared__ __align__(16) float ovls[4][64];
  __shared__ __align__(16) float g1ls[4][64];
  __shared__ __align__(16) float t1ls[4][128];
  __shared__ float gls[4][8];
  __shared__ float pls[4][4];

  const int w = threadIdx.x >> 6, lane = threadIdx.x & 63;
  const int b = blockIdx.x * 4 + w;

  hfls[w][lane] = h[b*64 + lane];
  #pragma unroll
  for (int t = 0; t < 16; ++t)
    nls[w][t][lane] = nhp[b*1024 + t*64 + lane];
  __syncthreads();

  float Q = soc_in_b[lane];
  #pragma unroll 4
  for (int dc = 0; dc < 16; ++dc)
    Q += dot4(*reinterpret_cast<const float4*>(&hfls[w][dc*4]), sInP[dc*192 + lane]);

  float Kv[16], Vv[16];
  {
    float bk = soc_in_b[64 + lane], bv = soc_in_b[128 + lane];
    #pragma unroll
    for (int k = 0; k < 16; ++k) { Kv[k] = bk; Vv[k] = bv; }
  }
  #pragma unroll 4
  for (int dc = 0; dc < 16; ++dc) {
    float4 wk = sInP[dc*192 + 64  + lane];
    float4 wv = sInP[dc*192 + 128 + lane];
    #pragma unroll
    for (int k = 0; k < 16; ++k) {
      float4 nv = *reinterpret_cast<const float4*>(&nls[w][k][dc*4]);
      Kv[k] += dot4(nv, wk);
      Vv[k] += dot4(nv, wv);
    }
  }
  qls[w][lane] = Q;
  #pragma unroll
  for (int k = 0; k < 16; ++k) kls[w][k][lane] = Kv[k];
  __syncthreads();

  {
    const int shh = lane >> 4, kk = lane & 15;
    float sc = 0.f;
    #pragma unroll
    for (int hd = 0; hd < 16; ++hd)
      sc += qls[w][shh*16 + hd] * kls[w][kk][shh*16 + hd];
    sc *= 0.25f;
    float m = sc;
    #pragma unroll
    for (int off = 1; off < 16; off <<= 1) m = fmaxf(m, __shfl_xor(m, off));
    float e = __expf(sc - m);
    float sm = e;
    #pragma unroll
    for (int off = 1; off < 16; off <<= 1) sm += __shfl_xor(sm, off);
    float a = e / sm;
    als[w][lane] = a;
    float am = a + __shfl_xor(a, 16);
    am += __shfl_xor(am, 32);
    if (lane < 16) out[OUT_ATTN + b*16 + lane] = 0.25f * am;
  }
  __syncthreads();

  {
    float ov = 0.f;
    #pragma unroll
    for (int k = 0; k < 16; ++k)
      ov += als[w][(lane & ~15) + k] * Vv[k];
    ovls[w][lane] = ov;
  }
  __syncthreads();
  {
    float soc = soc_out_b[lane];
    #pragma unroll 4
    for (int dc = 0; dc < 16; ++dc)
      soc += dot4(*reinterpret_cast<const float4*>(&ovls[w][dc*4]), sOutP[dc*64 + lane]);
    hfls[w][64 + lane] = soc;
  }
  __syncthreads();

  {
    float g1 = goal1_b[lane];
    #pragma unroll 4
    for (int dc = 0; dc < 32; ++dc)
      g1 += dot4(*reinterpret_cast<const float4*>(&hfls[w][dc*4]), g1P[dc*64 + lane]);
    g1ls[w][lane] = fmaxf(g1, 0.f);
  }
  __syncthreads();

  if (lane < 6) {
    float gv = goal2_b[lane];
    #pragma unroll 4
    for (int dc = 0; dc < 16; ++dc)
      gv += dot4(*reinterpret_cast<const float4*>(&g1ls[w][dc*4]), g2P[dc*6 + lane]);
    gls[w][lane] = gv;
    out[OUT_GOALS + b*6 + lane] = gv;
  } else if (lane >= 8 && lane < 11) {
    const int o = lane - 8;
    float pv = prob_b[o];
    #pragma unroll 4
    for (int dc = 0; dc < 32; ++dc)
      pv += dot4(*reinterpret_cast<const float4*>(&hfls[w][dc*4]), pP[dc*3 + o]);
    pls[w][o] = pv;
  }
  __syncthreads();
  if (lane < 3) {
    float p0 = pls[w][0], p1 = pls[w][1], p2 = pls[w][2];
    float mx = fmaxf(p0, fmaxf(p1, p2));
    float e0 = __expf(p0 - mx), e1 = __expf(p1 - mx), e2 = __expf(p2 - mx);
    float mine = (lane == 0) ? e0 : ((lane == 1) ? e1 : e2);
    out[OUT_PROBS + b*3 + lane] = mine / (e0 + e1 + e2);
  }

  for (int k3 = 0; k3 < 3; ++k3) {
    const float gx = gls[w][k3*2], gy = gls[w][k3*2 + 1];
    float t0 = traj1_b[lane], t1v = traj1_b[64 + lane];
    #pragma unroll 4
    for (int dc = 0; dc < 32; ++dc) {
      float4 xv = *reinterpret_cast<const float4*>(&hfls[w][dc*4]);
      t0  += dot4(xv, t1P[dc*128 + lane]);
      t1v += dot4(xv, t1P[dc*128 + 64 + lane]);
    }
    t0  += gx * t1T[lane*2]      + gy * t1T[lane*2 + 1];
    t1v += gx * t1T[(64+lane)*2] + gy * t1T[(64+lane)*2 + 1];
    t1ls[w][lane]      = fmaxf(t0, 0.f);
    t1ls[w][64 + lane] = fmaxf(t1v, 0.f);
    __syncthreads();
    if (lane < 24) {
      float tv = traj2_b[lane];
      #pragma unroll 4
      for (int dc = 0; dc < 32; ++dc)
        tv += dot4(*reinterpret_cast<const float4*>(&t1ls[w][dc*4]), t2P[dc*24 + lane]);
      out[OUT_TRAJ + b*72 + k3*24 + lane] = tv;
    }
    __syncthreads();
  }
}

// ---------------------------------------------------------------------------
extern "C" void kernel_launch(void* const* d_in, const int* in_sizes, int n_in,
                              void* d_out, int out_size, void* d_ws, size_t ws_size,
                              hipStream_t stream) {
  const float* xin        = (const float*)d_in[0];
  const float* neighbors  = (const float*)d_in[1];
  const float* pe         = (const float*)d_in[2];
  const float* embed_w    = (const float*)d_in[3];
  const float* embed_b    = (const float*)d_in[4];
  const float* attn_in_w  = (const float*)d_in[5];
  const float* attn_in_b  = (const float*)d_in[6];
  const float* attn_out_w = (const float*)d_in[7];
  const float* attn_out_b = (const float*)d_in[8];
  const float* ff1_w      = (const float*)d_in[9];
  const float* ff1_b      = (const float*)d_in[10];
  const float* ff2_w      = (const float*)d_in[11];
  const float* ff2_b      = (const float*)d_in[12];
  const float* ln1_g      = (const float*)d_in[13];
  const float* ln1_b      = (const float*)d_in[14];
  const float* ln2_g      = (const float*)d_in[15];
  const float* ln2_b      = (const float*)d_in[16];
  const float* soc_in_w   = (const float*)d_in[17];
  const float* soc_in_b   = (const float*)d_in[18];
  const float* soc_out_w  = (const float*)d_in[19];
  const float* soc_out_b  = (const float*)d_in[20];
  const float* goal1_w    = (const float*)d_in[21];
  const float* goal1_b    = (const float*)d_in[22];
  const float* goal2_w    = (const float*)d_in[23];
  const float* goal2_b    = (const float*)d_in[24];
  const float* traj1_w    = (const float*)d_in[25];
  const float* traj1_b    = (const float*)d_in[26];
  const float* traj2_w    = (const float*)d_in[27];
  const float* traj2_b    = (const float*)d_in[28];
  const float* prob_w     = (const float*)d_in[29];
  const float* prob_b     = (const float*)d_in[30];

  float* ws  = (float*)d_ws;
  float* out = (float*)d_out;

  prep_consts<<<10, 256, 0, stream>>>(embed_w, embed_b, pe, attn_in_b,
      attn_out_b, ff1_b, ff2_b, ln1_g, ln1_b, ln2_g, ln2_b, ws);
  prep_social<<<176, 256, 0, stream>>>(soc_in_w, soc_out_w, goal1_w, goal2_w,
      traj1_w, traj2_w, prob_w, ws);
  prep_mfma<<<384, 256, 0, stream>>>(attn_in_w, attn_out_w, ff1_w, ff2_w, ws);

  encode_kernel<<<NSEQ/16, 256, 0, stream>>>(xin, neighbors, ws, ws + WS_H);

  social_head_kernel<<<B_EGO/4, 256, 0, stream>>>(
      ws, soc_in_b, soc_out_b, goal1_b, goal2_b, traj1_b, traj2_b, prob_b, out);
}